// Round 19
// baseline (109.291 us; speedup 1.0000x reference)
//
#include <hip/hip_runtime.h>
#include <stdint.h>

// DiT self-attention: B=2, S=2048, H=1024, NH=16, HD=64. fp32 in/out.
// cvt(fp32->bf16, flat 1D) -> fused QKV GEMM (128x128, 4 waves, 64x64 wave
// tile, 3-slot LDS rotation, depth-2 counted vmcnt) -> flash attn (2-WAVE
// 64q blocks, 32KB LDS -> 4 blocks/CU in 4 independent barrier domains;
// R14 in-phase schedule: stage-early + single syncthreads, K/V 2-slot dbuf;
// no-max exp2 softmax, MFMA lsum, key-permuted V^T) ->
// O GEMM (BM=64 x BN=128, 3-slot).

#define HH 1024
#define NHEAD 16
#define HDIM 64
#define SEQ 2048
#define NB 2
#define MTOT (NB * SEQ)  // 4096
#define QSCALE 0.1803368801111204f  // 0.125 * log2(e): exp2-domain softmax
#define BK 32

typedef unsigned short u16;
typedef __attribute__((ext_vector_type(8))) short bf16x8;   // MFMA A/B frag
typedef __attribute__((ext_vector_type(4))) float f32x4;    // MFMA C/D frag

static __device__ __forceinline__ float exp2_raw(float x) {
  float r; asm("v_exp_f32 %0, %1" : "=v"(r) : "v"(x)); return r;
}
static __device__ __forceinline__ uint32_t cvtpk_bf16(float lo, float hi) {
  uint32_t r; asm("v_cvt_pk_bf16_f32 %0, %1, %2" : "=v"(r) : "v"(lo), "v"(hi)); return r;
}
// async global->LDS, 16B/lane, dest = wave-uniform base + lane*16 (linear)
static __device__ __forceinline__ void gload16(const u16* g, u16* l) {
  __builtin_amdgcn_global_load_lds(
      (const __attribute__((address_space(1))) uint32_t*)(const void*)g,
      (__attribute__((address_space(3))) uint32_t*)(void*)l, 16, 0, 0);
}
#define VMW(N) asm volatile("s_waitcnt vmcnt(" #N ")" ::: "memory")
static __device__ __forceinline__ void bar() {  // raw barrier, no vmcnt(0) drain
  asm volatile("" ::: "memory");
  __builtin_amdgcn_s_barrier();
  asm volatile("" ::: "memory");
}

// XOR swizzle for [R][64] u16 LDS tiles (attn; 128B rows): flips byte bits 4..6
#define SWZ(row, col) (((row) * 64) + ((col) ^ (((row) & 7) << 3)))

// ---------------- fp32 -> bf16 bulk convert, flat 1D (Xb|Wall contiguous) ----
__global__ void cvt_all_kernel(const float* __restrict__ hs,
                               const float* __restrict__ w0, const float* __restrict__ w1,
                               const float* __restrict__ w2, const float* __restrict__ w3,
                               u16* __restrict__ dst) {
  const int NX = MTOT * HH / 4;   // X float4s
  const int NW = HH * HH / 4;     // per-weight float4s
  int i = blockIdx.x * 256 + threadIdx.x;   // total NX + 4*NW = 2097152
  const float* s; int j;
  if (i < NX) { s = hs; j = i; }
  else {
    int w = (i - NX) >> 18;       // / NW (262144)
    j = (i - NX) & (NW - 1);
    s = (w == 0) ? w0 : (w == 1) ? w1 : (w == 2) ? w2 : w3;
  }
  float4 v = reinterpret_cast<const float4*>(s)[j];
  uint2 o;
  o.x = cvtpk_bf16(v.x, v.y);
  o.y = cvtpk_bf16(v.z, v.w);
  reinterpret_cast<uint2*>(dst)[i] = o;
}

// ---------------- QKV GEMM: 128x128 tile, 4 waves (2M x 2N, wave = 64x64),
// BK=32, 3-slot LDS rotation (48 KB -> 3 blocks/CU), depth-2 counted vmcnt.
// W=[3072][1024]; block mode = bcol>>10 (0:Q*QSCALE, 1:K, 2:V^T perm).
__global__ __launch_bounds__(256, 3)
void gemm_qkv_kernel(const u16* __restrict__ A, const u16* __restrict__ W,
                     const float* __restrict__ bq, const float* __restrict__ bk,
                     const float* __restrict__ bv,
                     u16* __restrict__ outQ, u16* __restrict__ outK, u16* __restrict__ outVT)
{
  const int tid  = threadIdx.x;
  const int lane = tid & 63, wave = tid >> 6;   // 4 waves
  const int wm = wave >> 1, wn = wave & 1;      // 2 (M) x 2 (N)
  const int l15 = lane & 15, l4 = lane >> 4;
  const int brow = blockIdx.x * 128, bcol = blockIdx.y * 128;

  __shared__ __align__(16) u16 lA[3][128 * BK];
  __shared__ __align__(16) u16 lB[3][128 * BK];

  const int sr = wave * 16 + (lane >> 2);
  const int sc = (lane & 3) ^ ((sr >> 1) & 3);
  const u16* gA0 = A + (size_t)(brow + sr) * HH + sc * 8;
  const u16* gA1 = A + (size_t)(brow + sr + 64) * HH + sc * 8;
  const u16* gB0 = W + (size_t)(bcol + sr) * HH + sc * 8;
  const u16* gB1 = W + (size_t)(bcol + sr + 64) * HH + sc * 8;

#define STAGEQ(slot, kt)                                                      \
  { gload16(gA0 + (kt) * BK, (u16*)((char*)&lA[slot][0] + wave * 1024));      \
    gload16(gA1 + (kt) * BK, (u16*)((char*)&lA[slot][0] + 4096 + wave * 1024)); \
    gload16(gB0 + (kt) * BK, (u16*)((char*)&lB[slot][0] + wave * 1024));      \
    gload16(gB1 + (kt) * BK, (u16*)((char*)&lB[slot][0] + 4096 + wave * 1024)); }

  int aoff[4], boff[4];
#pragma unroll
  for (int mr = 0; mr < 4; ++mr) {
    int r = wm * 64 + mr * 16 + l15;
    aoff[mr] = r * BK + ((l4 ^ ((r >> 1) & 3)) * 8);
  }
#pragma unroll
  for (int nr = 0; nr < 4; ++nr) {
    int r = wn * 64 + nr * 16 + l15;
    boff[nr] = r * BK + ((l4 ^ ((r >> 1) & 3)) * 8);
  }

  f32x4 acc[4][4];
#pragma unroll
  for (int mr = 0; mr < 4; ++mr)
#pragma unroll
    for (int nr = 0; nr < 4; ++nr) acc[mr][nr] = (f32x4){0.f, 0.f, 0.f, 0.f};

  STAGEQ(0, 0);
  STAGEQ(1, 1);

  for (int k = 0; k < 32; ++k) {
    if (k < 31) VMW(4); else VMW(0);
    bar();

    if (k + 2 < 32) STAGEQ((k + 2) % 3, k + 2);

    const u16* sA = &lA[k % 3][0];
    const u16* sB = &lB[k % 3][0];
    bf16x8 a[4], b[4];
#pragma unroll
    for (int nr = 0; nr < 4; ++nr) b[nr] = *reinterpret_cast<const bf16x8*>(sB + boff[nr]);
#pragma unroll
    for (int mr = 0; mr < 4; ++mr) a[mr] = *reinterpret_cast<const bf16x8*>(sA + aoff[mr]);

    __builtin_amdgcn_s_setprio(1);
#pragma unroll
    for (int mr = 0; mr < 4; ++mr)
#pragma unroll
      for (int nr = 0; nr < 4; ++nr)
        acc[mr][nr] = __builtin_amdgcn_mfma_f32_16x16x32_bf16(a[mr], b[nr], acc[mr][nr], 0, 0, 0);
    __builtin_amdgcn_s_setprio(0);
  }
#undef STAGEQ

  const int mode = bcol >> 10;
#pragma unroll
  for (int mr = 0; mr < 4; ++mr) {
    int m0 = brow + wm * 64 + mr * 16 + l4 * 4;
    int bb = m0 >> 11, s0 = m0 & (SEQ - 1);
#pragma unroll
    for (int nr = 0; nr < 4; ++nr) {
      int n = bcol + wn * 64 + nr * 16 + l15;
      int nn = n & (HH - 1);
      int h = nn >> 6, d = nn & (HDIM - 1);
      float bias_n = (mode == 0) ? bq[nn] : (mode == 1) ? bk[nn] : bv[nn];
      if (mode == 2) {
        int p0 = (s0 & ~31) | (((s0 >> 2) & 3) << 3) | (((s0 >> 4) & 1) << 2);
        uint2 pk4;
        pk4.x = cvtpk_bf16(acc[mr][nr][0] + bias_n, acc[mr][nr][1] + bias_n);
        pk4.y = cvtpk_bf16(acc[mr][nr][2] + bias_n, acc[mr][nr][3] + bias_n);
        *reinterpret_cast<uint2*>(&outVT[((size_t)(bb * NHEAD + h) * HDIM + d) * SEQ + p0]) = pk4;
      } else {
        u16* dst = (mode == 0) ? outQ : outK;
        float sc2 = (mode == 0) ? QSCALE : 1.0f;
        uint32_t r01 = cvtpk_bf16((acc[mr][nr][0] + bias_n) * sc2, (acc[mr][nr][1] + bias_n) * sc2);
        uint32_t r23 = cvtpk_bf16((acc[mr][nr][2] + bias_n) * sc2, (acc[mr][nr][3] + bias_n) * sc2);
        size_t base = ((size_t)(bb * NHEAD + h) * SEQ + s0) * HDIM + d;
        dst[base]            = (u16)r01;
        dst[base + HDIM]     = (u16)(r01 >> 16);
        dst[base + 2 * HDIM] = (u16)r23;
        dst[base + 3 * HDIM] = (u16)(r23 >> 16);
      }
    }
  }
}

// ---------------- O GEMM: BM=64 x BN=128, 4 waves (2M x 2N, wave = 32x64),
// BK=32, 3-slot rotation (36 KB), depth-2 counted vmcnt (3 loads/wave/step).
// Grid 64x8 = 512 blocks = 2 blocks/CU. fp32 out + bo.
__global__ __launch_bounds__(256, 3)
void gemm_o_kernel(const u16* __restrict__ A, const u16* __restrict__ W,
                   const float* __restrict__ bo, float* __restrict__ outF)
{
  const int tid  = threadIdx.x;
  const int lane = tid & 63, wave = tid >> 6;   // 4 waves
  const int wm = wave >> 1, wn = wave & 1;      // 2 (M: 32 rows) x 2 (N: 64 cols)
  const int l15 = lane & 15, l4 = lane >> 4;
  const int brow = blockIdx.x * 64, bcol = blockIdx.y * 128;

  __shared__ __align__(16) u16 lA[3][64 * BK];    // 3 x 4 KB
  __shared__ __align__(16) u16 lB[3][128 * BK];   // 3 x 8 KB (36 KB total)

  const int ra = wave * 16 + (lane >> 2);
  const u16* gAo = A + (size_t)(brow + ra) * HH + (((lane & 3) ^ ((ra >> 1) & 3)) * 8);
  const int rb0 = (wave * 2 + 0) * 16 + (lane >> 2);
  const int rb1 = (wave * 2 + 1) * 16 + (lane >> 2);
  const u16* gBo0 = W + (size_t)(bcol + rb0) * HH + (((lane & 3) ^ ((rb0 >> 1) & 3)) * 8);
  const u16* gBo1 = W + (size_t)(bcol + rb1) * HH + (((lane & 3) ^ ((rb1 >> 1) & 3)) * 8);

#define STAGEO(slot, kt)                                                      \
  { gload16(gAo  + (kt) * BK, &lA[slot][wave * 512]);                         \
    gload16(gBo0 + (kt) * BK, &lB[slot][(wave * 2 + 0) * 512]);               \
    gload16(gBo1 + (kt) * BK, &lB[slot][(wave * 2 + 1) * 512]); }

  int aoff[2], boff[4];
#pragma unroll
  for (int mr = 0; mr < 2; ++mr) {
    int r = wm * 32 + mr * 16 + l15;
    aoff[mr] = r * BK + ((l4 ^ ((r >> 1) & 3)) * 8);
  }
#pragma unroll
  for (int nr = 0; nr < 4; ++nr) {
    int r = wn * 64 + nr * 16 + l15;
    boff[nr] = r * BK + ((l4 ^ ((r >> 1) & 3)) * 8);
  }

  f32x4 acc[2][4];
#pragma unroll
  for (int mr = 0; mr < 2; ++mr)
#pragma unroll
    for (int nr = 0; nr < 4; ++nr) acc[mr][nr] = (f32x4){0.f, 0.f, 0.f, 0.f};

  STAGEO(0, 0);
  STAGEO(1, 1);

  for (int k = 0; k < 32; ++k) {
    if (k < 31) VMW(3); else VMW(0);
    bar();

    if (k + 2 < 32) STAGEO((k + 2) % 3, k + 2);

    const u16* sA = &lA[k % 3][0];
    const u16* sB = &lB[k % 3][0];
    bf16x8 a[2], b[4];
#pragma unroll
    for (int nr = 0; nr < 4; ++nr) b[nr] = *reinterpret_cast<const bf16x8*>(sB + boff[nr]);
#pragma unroll
    for (int mr = 0; mr < 2; ++mr) a[mr] = *reinterpret_cast<const bf16x8*>(sA + aoff[mr]);

    __builtin_amdgcn_s_setprio(1);
#pragma unroll
    for (int mr = 0; mr < 2; ++mr)
#pragma unroll
      for (int nr = 0; nr < 4; ++nr)
        acc[mr][nr] = __builtin_amdgcn_mfma_f32_16x16x32_bf16(a[mr], b[nr], acc[mr][nr], 0, 0, 0);
    __builtin_amdgcn_s_setprio(0);
  }
#undef STAGEO

#pragma unroll
  for (int mr = 0; mr < 2; ++mr) {
    int m0 = brow + wm * 32 + mr * 16 + l4 * 4;
#pragma unroll
    for (int nr = 0; nr < 4; ++nr) {
      int n = bcol + wn * 64 + nr * 16 + l15;
      float bias_n = bo[n];
#pragma unroll
      for (int t = 0; t < 4; ++t)
        outF[(size_t)(m0 + t) * HH + n] = acc[mr][nr][t] + bias_n;
    }
  }
}

// ---------------- flash attention: 2-WAVE blocks of 64 q (wave = 32 q, G=2),
// 32 KB LDS (K/V 2-slot dbuf) -> 4 blocks/CU CERTAIN (128 KB < 160 KB),
// 8 waves/CU in 4 independent barrier domains (breaks cross-wave lockstep).
// R14 in-phase schedule: stage(k+1) early, compute(k), single syncthreads.
// Swapped QK^T, no-max exp2 softmax, MFMA ones-row lsum, key-permuted V^T.
__global__ __launch_bounds__(128)
void attn_kernel(const u16* __restrict__ Qh, const u16* __restrict__ Kh,
                 const u16* __restrict__ VTh, u16* __restrict__ CTX)
{
  const int head = blockIdx.x;
  const int qb   = blockIdx.y;          // 64-row Q block (0..31)
  const int tid  = threadIdx.x;
  const int lane = tid & 63, wave = tid >> 6;   // 2 waves
  const int l15 = lane & 15, l4 = lane >> 4;

  __shared__ __align__(16) u16 lK[2][64 * 64];
  __shared__ __align__(16) u16 lV[2][64 * 64];   // 32 KB total

  const u16* Qg = Qh + ((size_t)head * SEQ + qb * 64 + wave * 32) * HDIM;
  const u16* Kg = Kh + (size_t)head * SEQ * HDIM;
  const u16* Vg = VTh + (size_t)head * HDIM * SEQ;

  // staging: wave w issue i covers LDS u16 pos (w*4+i)*512 + lane*8 =
  // (row = w*32 + i*8 + (lane>>3), swzcol = (lane&7)*8); source col
  // pre-swizzled so element (row,col) lands at SWZ(row,col): row&7 = lane>>3.
  const int scol = ((lane & 7) ^ (lane >> 3)) * 8;
  const u16* gk[4]; const u16* gv[4];
#pragma unroll
  for (int i = 0; i < 4; ++i) {
    int r = wave * 32 + i * 8 + (lane >> 3);
    gk[i] = Kg + (size_t)r * HDIM + scol;
    gv[i] = Vg + (size_t)r * SEQ + scol;
  }

#define KSTAGE(buf, kt)                                                       \
  { _Pragma("unroll")                                                         \
    for (int i = 0; i < 4; ++i)                                               \
      gload16(gk[i] + (size_t)(kt) * 64 * HDIM, &lK[buf][(wave * 4 + i) * 512]); }
#define VSTAGE(buf, kt)                                                       \
  { _Pragma("unroll")                                                         \
    for (int i = 0; i < 4; ++i)                                               \
      gload16(gv[i] + (kt) * 64, &lV[buf][(wave * 4 + i) * 512]); }

  bf16x8 qf[2][2];
#pragma unroll
  for (int g = 0; g < 2; ++g)
#pragma unroll
    for (int kk = 0; kk < 2; ++kk)
      qf[g][kk] = *reinterpret_cast<const bf16x8*>(&Qg[(g * 16 + l15) * HDIM + kk * 32 + l4 * 8]);

  int fi[2][4];
#pragma unroll
  for (int kk = 0; kk < 2; ++kk)
#pragma unroll
    for (int j = 0; j < 4; ++j)
      fi[kk][j] = SWZ(j * 16 + l15, kk * 32 + l4 * 8);

  KSTAGE(0, 0); VSTAGE(0, 0);
  __syncthreads();   // tile 0 staged & visible

  union { uint32_t u[4]; bf16x8 v; } ones;
#pragma unroll
  for (int t = 0; t < 4; ++t) ones.u[t] = 0x3F803F80u;

  f32x4 accO[2][4];   // [g][dj]: O^T col=l15=q, row d = dj*16 + l4*4 + t
  f32x4 accS[2];      // [g]: every element = lsum(q)
#pragma unroll
  for (int g = 0; g < 2; ++g) {
#pragma unroll
    for (int dj = 0; dj < 4; ++dj) accO[g][dj] = (f32x4){0.f, 0.f, 0.f, 0.f};
    accS[g] = (f32x4){0.f, 0.f, 0.f, 0.f};
  }

  for (int kb = 0; kb < SEQ / 64; ++kb) {
    const int cur = kb & 1;
    const bool pre = (kb + 1 < SEQ / 64);
    if (pre) { KSTAGE(cur ^ 1, kb + 1); VSTAGE(cur ^ 1, kb + 1); }  // async,
        // lands under this tile's compute; buffer safe (last read phase kb-1,
        // joined at the syncthreads that opened this phase)

    // K frags once per tile, shared across q-groups (8 ds_read_b128)
    bf16x8 kf[2][4];
#pragma unroll
    for (int kk = 0; kk < 2; ++kk)
#pragma unroll
      for (int kj = 0; kj < 4; ++kj)
        kf[kk][kj] = *reinterpret_cast<const bf16x8*>(&lK[cur][fi[kk][kj]]);

    // S^T = K Q^T per q-group; P = exp2(S) in-register (no max: scores O(3))
    union { uint32_t u[4]; bf16x8 v; } pfr[2][2];
#pragma unroll
    for (int g = 0; g < 2; ++g) {
      f32x4 sf[4];
#pragma unroll
      for (int kj = 0; kj < 4; ++kj) sf[kj] = (f32x4){0.f, 0.f, 0.f, 0.f};
      __builtin_amdgcn_s_setprio(1);
#pragma unroll
      for (int kk = 0; kk < 2; ++kk)
#pragma unroll
        for (int kj = 0; kj < 4; ++kj)
          sf[kj] = __builtin_amdgcn_mfma_f32_16x16x32_bf16(kf[kk][kj], qf[g][kk], sf[kj], 0, 0, 0);
      __builtin_amdgcn_s_setprio(0);
#pragma unroll
      for (int kj = 0; kj < 4; ++kj) {
        float p0 = exp2_raw(sf[kj][0]);
        float p1 = exp2_raw(sf[kj][1]);
        float p2 = exp2_raw(sf[kj][2]);
        float p3 = exp2_raw(sf[kj][3]);
        pfr[g][kj >> 1].u[(kj & 1) * 2 + 0] = cvtpk_bf16(p0, p1);
        pfr[g][kj >> 1].u[(kj & 1) * 2 + 1] = cvtpk_bf16(p2, p3);
      }
    }

    // O^T += V^T P^T; V^T key-permuted so lane's own P IS the B-frag.
#pragma unroll
    for (int kk = 0; kk < 2; ++kk) {
      bf16x8 vf[4];
#pragma unroll
      for (int dj = 0; dj < 4; ++dj)
        vf[dj] = *reinterpret_cast<const bf16x8*>(&lV[cur][fi[kk][dj]]);
      __builtin_amdgcn_s_setprio(1);
#pragma unroll
      for (int g = 0; g < 2; ++g) {
#pragma unroll
        for (int dj = 0; dj < 4; ++dj)
          accO[g][dj] = __builtin_amdgcn_mfma_f32_16x16x32_bf16(vf[dj], pfr[g][kk].v, accO[g][dj], 0, 0, 0);
        accS[g] = __builtin_amdgcn_mfma_f32_16x16x32_bf16(ones.v, pfr[g][kk].v, accS[g], 0, 0, 0);
      }
      __builtin_amdgcn_s_setprio(0);
    }

    if (pre) __syncthreads();   // vmcnt drain (stage issued pre-compute ->
                                // mostly hidden) + join: next tile ready
  }
#undef KSTAGE
#undef VSTAGE

  const int bb = head >> 4, h = head & (NHEAD - 1);
#pragma unroll
  for (int g = 0; g < 2; ++g) {
    const int sq = qb * 64 + wave * 32 + g * 16 + l15;
    float inv = 1.0f / accS[g][0];
#pragma unroll
    for (int dj = 0; dj < 4; ++dj) {
      uint2 o;
      o.x = cvtpk_bf16(accO[g][dj][0] * inv, accO[g][dj][1] * inv);
      o.y = cvtpk_bf16(accO[g][dj][2] * inv, accO[g][dj][3] * inv);
      *reinterpret_cast<uint2*>(&CTX[((size_t)(bb * SEQ + sq)) * HH + h * HDIM + dj * 16 + l4 * 4]) = o;
    }
  }
}

extern "C" void kernel_launch(void* const* d_in, const int* in_sizes, int n_in,
                              void* d_out, int out_size, void* d_ws, size_t ws_size,
                              hipStream_t stream) {
  const float* hs = (const float*)d_in[0];
  const float* Wq = (const float*)d_in[1];
  const float* bq = (const float*)d_in[2];
  const float* Wk = (const float*)d_in[3];
  const float* bk = (const float*)d_in[4];
  const float* Wv = (const float*)d_in[5];
  const float* bv = (const float*)d_in[6];
  const float* Wo = (const float*)d_in[7];
  const float* bo = (const float*)d_in[8];
  float* out = (float*)d_out;

  char* ws = (char*)d_ws;
  u16* Xb   = (u16*)(ws);                       // 8 MiB (X bf16)
  u16* Wall = (u16*)(ws + ((size_t)8 << 20));   // [Wq|Wk|Wv|Wo] bf16, contiguous after Xb
  u16* Qh   = (u16*)(ws + ((size_t)16 << 20));
  u16* Kh   = (u16*)(ws + ((size_t)24 << 20));
  u16* VT   = (u16*)(ws + ((size_t)32 << 20));
  u16* CT   = Xb;  // X dead after QKV GEMM

  const int nflt4 = MTOT * HH / 4 + HH * HH;    // X + 4 weights, float4 units
  cvt_all_kernel<<<dim3(nflt4 / 256), 256, 0, stream>>>(
      hs, Wq, Wk, Wv, Wo, (u16*)ws);

  gemm_qkv_kernel<<<dim3(MTOT / 128, 3 * HH / 128), 256, 0, stream>>>(
      Xb, Wall, bq, bk, bv, Qh, Kh, VT);

  attn_kernel<<<dim3(NB * NHEAD, SEQ / 64), 128, 0, stream>>>(Qh, Kh, VT, CT);

  gemm_o_kernel<<<dim3(MTOT / 64, HH / 128), 256, 0, stream>>>(
      CT, Wall + (size_t)3 * HH * HH, bo, out);
}

// Round 20
// 106.014 us; speedup vs baseline: 1.0309x; 1.0309x over previous
//
#include <hip/hip_runtime.h>
#include <stdint.h>

// DiT self-attention: B=2, S=2048, H=1024, NH=16, HD=64. fp32 in/out.
// BEST-KNOWN CONFIG (R17 consolidation):
// cvt(fp32->bf16, flat 1D) -> fused QKV GEMM (128x128, 4 waves, 64x64 wave
// tile, 3-slot LDS rotation, depth-2 counted vmcnt) -> flash attn (4-wave
// 128q blocks, G=2, gload_lds staging, 1-tile software pipeline: PV lags
// QK^T; V 3-slot, K 2-slot; no-max exp2 softmax, MFMA lsum, key-permuted
// V^T) -> O GEMM (BM=64 x BN=128, 512 blocks = 2/CU, 3-slot).

#define HH 1024
#define NHEAD 16
#define HDIM 64
#define SEQ 2048
#define NB 2
#define MTOT (NB * SEQ)  // 4096
#define QSCALE 0.1803368801111204f  // 0.125 * log2(e): exp2-domain softmax
#define BK 32

typedef unsigned short u16;
typedef __attribute__((ext_vector_type(8))) short bf16x8;   // MFMA A/B frag
typedef __attribute__((ext_vector_type(4))) float f32x4;    // MFMA C/D frag

static __device__ __forceinline__ float exp2_raw(float x) {
  float r; asm("v_exp_f32 %0, %1" : "=v"(r) : "v"(x)); return r;
}
static __device__ __forceinline__ uint32_t cvtpk_bf16(float lo, float hi) {
  uint32_t r; asm("v_cvt_pk_bf16_f32 %0, %1, %2" : "=v"(r) : "v"(lo), "v"(hi)); return r;
}
// async global->LDS, 16B/lane, dest = wave-uniform base + lane*16 (linear)
static __device__ __forceinline__ void gload16(const u16* g, u16* l) {
  __builtin_amdgcn_global_load_lds(
      (const __attribute__((address_space(1))) uint32_t*)(const void*)g,
      (__attribute__((address_space(3))) uint32_t*)(void*)l, 16, 0, 0);
}
#define VMW(N) asm volatile("s_waitcnt vmcnt(" #N ")" ::: "memory")
static __device__ __forceinline__ void bar() {  // raw barrier, no vmcnt(0) drain
  asm volatile("" ::: "memory");
  __builtin_amdgcn_s_barrier();
  asm volatile("" ::: "memory");
}

// XOR swizzle for [R][64] u16 LDS tiles (attn; 128B rows): flips byte bits 4..6
#define SWZ(row, col) (((row) * 64) + ((col) ^ (((row) & 7) << 3)))

// ---------------- fp32 -> bf16 bulk convert, flat 1D (Xb|Wall contiguous) ----
__global__ void cvt_all_kernel(const float* __restrict__ hs,
                               const float* __restrict__ w0, const float* __restrict__ w1,
                               const float* __restrict__ w2, const float* __restrict__ w3,
                               u16* __restrict__ dst) {
  const int NX = MTOT * HH / 4;   // X float4s
  const int NW = HH * HH / 4;     // per-weight float4s
  int i = blockIdx.x * 256 + threadIdx.x;   // total NX + 4*NW = 2097152
  const float* s; int j;
  if (i < NX) { s = hs; j = i; }
  else {
    int w = (i - NX) >> 18;       // / NW (262144)
    j = (i - NX) & (NW - 1);
    s = (w == 0) ? w0 : (w == 1) ? w1 : (w == 2) ? w2 : w3;
  }
  float4 v = reinterpret_cast<const float4*>(s)[j];
  uint2 o;
  o.x = cvtpk_bf16(v.x, v.y);
  o.y = cvtpk_bf16(v.z, v.w);
  reinterpret_cast<uint2*>(dst)[i] = o;
}

// ---------------- QKV GEMM: 128x128 tile, 4 waves (2M x 2N, wave = 64x64),
// BK=32, 3-slot LDS rotation (48 KB -> 3 blocks/CU), depth-2 counted vmcnt.
// W=[3072][1024]; block mode = bcol>>10 (0:Q*QSCALE, 1:K, 2:V^T perm).
__global__ __launch_bounds__(256, 3)
void gemm_qkv_kernel(const u16* __restrict__ A, const u16* __restrict__ W,
                     const float* __restrict__ bq, const float* __restrict__ bk,
                     const float* __restrict__ bv,
                     u16* __restrict__ outQ, u16* __restrict__ outK, u16* __restrict__ outVT)
{
  const int tid  = threadIdx.x;
  const int lane = tid & 63, wave = tid >> 6;   // 4 waves
  const int wm = wave >> 1, wn = wave & 1;      // 2 (M) x 2 (N)
  const int l15 = lane & 15, l4 = lane >> 4;
  const int brow = blockIdx.x * 128, bcol = blockIdx.y * 128;

  __shared__ __align__(16) u16 lA[3][128 * BK];
  __shared__ __align__(16) u16 lB[3][128 * BK];

  const int sr = wave * 16 + (lane >> 2);
  const int sc = (lane & 3) ^ ((sr >> 1) & 3);
  const u16* gA0 = A + (size_t)(brow + sr) * HH + sc * 8;
  const u16* gA1 = A + (size_t)(brow + sr + 64) * HH + sc * 8;
  const u16* gB0 = W + (size_t)(bcol + sr) * HH + sc * 8;
  const u16* gB1 = W + (size_t)(bcol + sr + 64) * HH + sc * 8;

#define STAGEQ(slot, kt)                                                      \
  { gload16(gA0 + (kt) * BK, (u16*)((char*)&lA[slot][0] + wave * 1024));      \
    gload16(gA1 + (kt) * BK, (u16*)((char*)&lA[slot][0] + 4096 + wave * 1024)); \
    gload16(gB0 + (kt) * BK, (u16*)((char*)&lB[slot][0] + wave * 1024));      \
    gload16(gB1 + (kt) * BK, (u16*)((char*)&lB[slot][0] + 4096 + wave * 1024)); }

  int aoff[4], boff[4];
#pragma unroll
  for (int mr = 0; mr < 4; ++mr) {
    int r = wm * 64 + mr * 16 + l15;
    aoff[mr] = r * BK + ((l4 ^ ((r >> 1) & 3)) * 8);
  }
#pragma unroll
  for (int nr = 0; nr < 4; ++nr) {
    int r = wn * 64 + nr * 16 + l15;
    boff[nr] = r * BK + ((l4 ^ ((r >> 1) & 3)) * 8);
  }

  f32x4 acc[4][4];
#pragma unroll
  for (int mr = 0; mr < 4; ++mr)
#pragma unroll
    for (int nr = 0; nr < 4; ++nr) acc[mr][nr] = (f32x4){0.f, 0.f, 0.f, 0.f};

  STAGEQ(0, 0);
  STAGEQ(1, 1);

  for (int k = 0; k < 32; ++k) {
    if (k < 31) VMW(4); else VMW(0);
    bar();

    if (k + 2 < 32) STAGEQ((k + 2) % 3, k + 2);

    const u16* sA = &lA[k % 3][0];
    const u16* sB = &lB[k % 3][0];
    bf16x8 a[4], b[4];
#pragma unroll
    for (int nr = 0; nr < 4; ++nr) b[nr] = *reinterpret_cast<const bf16x8*>(sB + boff[nr]);
#pragma unroll
    for (int mr = 0; mr < 4; ++mr) a[mr] = *reinterpret_cast<const bf16x8*>(sA + aoff[mr]);

    __builtin_amdgcn_s_setprio(1);
#pragma unroll
    for (int mr = 0; mr < 4; ++mr)
#pragma unroll
      for (int nr = 0; nr < 4; ++nr)
        acc[mr][nr] = __builtin_amdgcn_mfma_f32_16x16x32_bf16(a[mr], b[nr], acc[mr][nr], 0, 0, 0);
    __builtin_amdgcn_s_setprio(0);
  }
#undef STAGEQ

  const int mode = bcol >> 10;
#pragma unroll
  for (int mr = 0; mr < 4; ++mr) {
    int m0 = brow + wm * 64 + mr * 16 + l4 * 4;
    int bb = m0 >> 11, s0 = m0 & (SEQ - 1);
#pragma unroll
    for (int nr = 0; nr < 4; ++nr) {
      int n = bcol + wn * 64 + nr * 16 + l15;
      int nn = n & (HH - 1);
      int h = nn >> 6, d = nn & (HDIM - 1);
      float bias_n = (mode == 0) ? bq[nn] : (mode == 1) ? bk[nn] : bv[nn];
      if (mode == 2) {
        int p0 = (s0 & ~31) | (((s0 >> 2) & 3) << 3) | (((s0 >> 4) & 1) << 2);
        uint2 pk4;
        pk4.x = cvtpk_bf16(acc[mr][nr][0] + bias_n, acc[mr][nr][1] + bias_n);
        pk4.y = cvtpk_bf16(acc[mr][nr][2] + bias_n, acc[mr][nr][3] + bias_n);
        *reinterpret_cast<uint2*>(&outVT[((size_t)(bb * NHEAD + h) * HDIM + d) * SEQ + p0]) = pk4;
      } else {
        u16* dst = (mode == 0) ? outQ : outK;
        float sc2 = (mode == 0) ? QSCALE : 1.0f;
        uint32_t r01 = cvtpk_bf16((acc[mr][nr][0] + bias_n) * sc2, (acc[mr][nr][1] + bias_n) * sc2);
        uint32_t r23 = cvtpk_bf16((acc[mr][nr][2] + bias_n) * sc2, (acc[mr][nr][3] + bias_n) * sc2);
        size_t base = ((size_t)(bb * NHEAD + h) * SEQ + s0) * HDIM + d;
        dst[base]            = (u16)r01;
        dst[base + HDIM]     = (u16)(r01 >> 16);
        dst[base + 2 * HDIM] = (u16)r23;
        dst[base + 3 * HDIM] = (u16)(r23 >> 16);
      }
    }
  }
}

// ---------------- O GEMM: BM=64 x BN=128, 4 waves (2M x 2N, wave = 32x64),
// BK=32, 3-slot rotation (36 KB), depth-2 counted vmcnt (3 loads/wave/step).
// Grid 64x8 = 512 blocks = 2 blocks/CU. fp32 out + bo.
__global__ __launch_bounds__(256, 3)
void gemm_o_kernel(const u16* __restrict__ A, const u16* __restrict__ W,
                   const float* __restrict__ bo, float* __restrict__ outF)
{
  const int tid  = threadIdx.x;
  const int lane = tid & 63, wave = tid >> 6;   // 4 waves
  const int wm = wave >> 1, wn = wave & 1;      // 2 (M: 32 rows) x 2 (N: 64 cols)
  const int l15 = lane & 15, l4 = lane >> 4;
  const int brow = blockIdx.x * 64, bcol = blockIdx.y * 128;

  __shared__ __align__(16) u16 lA[3][64 * BK];    // 3 x 4 KB
  __shared__ __align__(16) u16 lB[3][128 * BK];   // 3 x 8 KB (36 KB total)

  const int ra = wave * 16 + (lane >> 2);
  const u16* gAo = A + (size_t)(brow + ra) * HH + (((lane & 3) ^ ((ra >> 1) & 3)) * 8);
  const int rb0 = (wave * 2 + 0) * 16 + (lane >> 2);
  const int rb1 = (wave * 2 + 1) * 16 + (lane >> 2);
  const u16* gBo0 = W + (size_t)(bcol + rb0) * HH + (((lane & 3) ^ ((rb0 >> 1) & 3)) * 8);
  const u16* gBo1 = W + (size_t)(bcol + rb1) * HH + (((lane & 3) ^ ((rb1 >> 1) & 3)) * 8);

#define STAGEO(slot, kt)                                                      \
  { gload16(gAo  + (kt) * BK, &lA[slot][wave * 512]);                         \
    gload16(gBo0 + (kt) * BK, &lB[slot][(wave * 2 + 0) * 512]);               \
    gload16(gBo1 + (kt) * BK, &lB[slot][(wave * 2 + 1) * 512]); }

  int aoff[2], boff[4];
#pragma unroll
  for (int mr = 0; mr < 2; ++mr) {
    int r = wm * 32 + mr * 16 + l15;
    aoff[mr] = r * BK + ((l4 ^ ((r >> 1) & 3)) * 8);
  }
#pragma unroll
  for (int nr = 0; nr < 4; ++nr) {
    int r = wn * 64 + nr * 16 + l15;
    boff[nr] = r * BK + ((l4 ^ ((r >> 1) & 3)) * 8);
  }

  f32x4 acc[2][4];
#pragma unroll
  for (int mr = 0; mr < 2; ++mr)
#pragma unroll
    for (int nr = 0; nr < 4; ++nr) acc[mr][nr] = (f32x4){0.f, 0.f, 0.f, 0.f};

  STAGEO(0, 0);
  STAGEO(1, 1);

  for (int k = 0; k < 32; ++k) {
    if (k < 31) VMW(3); else VMW(0);
    bar();

    if (k + 2 < 32) STAGEO((k + 2) % 3, k + 2);

    const u16* sA = &lA[k % 3][0];
    const u16* sB = &lB[k % 3][0];
    bf16x8 a[2], b[4];
#pragma unroll
    for (int nr = 0; nr < 4; ++nr) b[nr] = *reinterpret_cast<const bf16x8*>(sB + boff[nr]);
#pragma unroll
    for (int mr = 0; mr < 2; ++mr) a[mr] = *reinterpret_cast<const bf16x8*>(sA + aoff[mr]);

    __builtin_amdgcn_s_setprio(1);
#pragma unroll
    for (int mr = 0; mr < 2; ++mr)
#pragma unroll
      for (int nr = 0; nr < 4; ++nr)
        acc[mr][nr] = __builtin_amdgcn_mfma_f32_16x16x32_bf16(a[mr], b[nr], acc[mr][nr], 0, 0, 0);
    __builtin_amdgcn_s_setprio(0);
  }
#undef STAGEO

#pragma unroll
  for (int mr = 0; mr < 2; ++mr) {
    int m0 = brow + wm * 32 + mr * 16 + l4 * 4;
#pragma unroll
    for (int nr = 0; nr < 4; ++nr) {
      int n = bcol + wn * 64 + nr * 16 + l15;
      float bias_n = bo[n];
#pragma unroll
      for (int t = 0; t < 4; ++t)
        outF[(size_t)(m0 + t) * HH + n] = acc[mr][nr][t] + bias_n;
    }
  }
}

// ---------------- flash attention (best-known, R15/R17): 4-wave blocks of
// 128 q (wave = 32 q, G=2), 1-tile software pipeline (PV lags QK^T);
// K 2-slot, V 3-slot; gload_lds with pre-swizzled source; no-max exp2
// softmax, MFMA ones-row lsum, key-permuted V^T.
__global__ __launch_bounds__(256)
void attn_kernel(const u16* __restrict__ Qh, const u16* __restrict__ Kh,
                 const u16* __restrict__ VTh, u16* __restrict__ CTX)
{
  const int head = blockIdx.x;
  const int qb   = blockIdx.y;
  const int tid  = threadIdx.x;
  const int lane = tid & 63, wave = tid >> 6;
  const int l15 = lane & 15, l4 = lane >> 4;

  __shared__ __align__(16) u16 lK[2][64 * 64];
  __shared__ __align__(16) u16 lV[3][64 * 64];

  const u16* Qg = Qh + ((size_t)head * SEQ + qb * 128 + wave * 32) * HDIM;
  const u16* Kg = Kh + (size_t)head * SEQ * HDIM;
  const u16* Vg = VTh + (size_t)head * HDIM * SEQ;

  const int srow = wave * 16 + (lane >> 3);
  const int scol = ((lane & 7) ^ (lane >> 3)) * 8;
  const u16* gk0 = Kg + (size_t)srow * HDIM + scol;
  const u16* gk1 = gk0 + 8 * HDIM;
  const u16* gv0 = Vg + (size_t)srow * SEQ + scol;
  const u16* gv1 = gv0 + 8 * SEQ;

#define KSTAGE(buf, kt)                                                       \
  { gload16(gk0 + (size_t)(kt) * 64 * HDIM, &lK[buf][(wave * 2 + 0) * 512]);  \
    gload16(gk1 + (size_t)(kt) * 64 * HDIM, &lK[buf][(wave * 2 + 1) * 512]); }
#define VSTAGE(buf, kt)                                                       \
  { gload16(gv0 + (kt) * 64, &lV[buf][(wave * 2 + 0) * 512]);                 \
    gload16(gv1 + (kt) * 64, &lV[buf][(wave * 2 + 1) * 512]); }

  bf16x8 qf[2][2];
#pragma unroll
  for (int g = 0; g < 2; ++g)
#pragma unroll
    for (int kk = 0; kk < 2; ++kk)
      qf[g][kk] = *reinterpret_cast<const bf16x8*>(&Qg[(g * 16 + l15) * HDIM + kk * 32 + l4 * 8]);

  int fi[2][4];
#pragma unroll
  for (int kk = 0; kk < 2; ++kk)
#pragma unroll
    for (int j = 0; j < 4; ++j)
      fi[kk][j] = SWZ(j * 16 + l15, kk * 32 + l4 * 8);

  KSTAGE(0, 0); VSTAGE(0, 0);
  __syncthreads();

  union { uint32_t u[4]; bf16x8 v; } ones;
#pragma unroll
  for (int t = 0; t < 4; ++t) ones.u[t] = 0x3F803F80u;

  f32x4 accO[2][4];
  f32x4 accS[2];
#pragma unroll
  for (int g = 0; g < 2; ++g) {
#pragma unroll
    for (int dj = 0; dj < 4; ++dj) accO[g][dj] = (f32x4){0.f, 0.f, 0.f, 0.f};
    accS[g] = (f32x4){0.f, 0.f, 0.f, 0.f};
  }

  union PU { uint32_t u[4]; bf16x8 v; };
  PU pfrA[2][2], pfrB[2][2];

#define QKT_EXP(PFR, kbuf)                                                    \
  {                                                                           \
    bf16x8 kf[2][4];                                                          \
    _Pragma("unroll")                                                         \
    for (int kk = 0; kk < 2; ++kk)                                            \
      _Pragma("unroll")                                                       \
      for (int kj = 0; kj < 4; ++kj)                                          \
        kf[kk][kj] = *reinterpret_cast<const bf16x8*>(&lK[kbuf][fi[kk][kj]]); \
    _Pragma("unroll")                                                         \
    for (int g = 0; g < 2; ++g) {                                             \
      f32x4 sf[4];                                                            \
      _Pragma("unroll")                                                       \
      for (int kj = 0; kj < 4; ++kj) sf[kj] = (f32x4){0.f, 0.f, 0.f, 0.f};    \
      __builtin_amdgcn_s_setprio(1);                                          \
      _Pragma("unroll")                                                       \
      for (int kk = 0; kk < 2; ++kk)                                          \
        _Pragma("unroll")                                                     \
        for (int kj = 0; kj < 4; ++kj)                                        \
          sf[kj] = __builtin_amdgcn_mfma_f32_16x16x32_bf16(kf[kk][kj], qf[g][kk], sf[kj], 0, 0, 0); \
      __builtin_amdgcn_s_setprio(0);                                          \
      _Pragma("unroll")                                                       \
      for (int kj = 0; kj < 4; ++kj) {                                        \
        float p0 = exp2_raw(sf[kj][0]);                                       \
        float p1 = exp2_raw(sf[kj][1]);                                       \
        float p2 = exp2_raw(sf[kj][2]);                                       \
        float p3 = exp2_raw(sf[kj][3]);                                       \
        PFR[g][kj >> 1].u[(kj & 1) * 2 + 0] = cvtpk_bf16(p0, p1);             \
        PFR[g][kj >> 1].u[(kj & 1) * 2 + 1] = cvtpk_bf16(p2, p3);             \
      }                                                                       \
    }                                                                         \
  }

#define PV(PFR, vslot)                                                        \
  {                                                                           \
    _Pragma("unroll")                                                         \
    for (int kk = 0; kk < 2; ++kk) {                                          \
      bf16x8 vf[4];                                                           \
      _Pragma("unroll")                                                       \
      for (int dj = 0; dj < 4; ++dj)                                          \
        vf[dj] = *reinterpret_cast<const bf16x8*>(&lV[vslot][fi[kk][dj]]);    \
      __builtin_amdgcn_s_setprio(1);                                          \
      _Pragma("unroll")                                                       \
      for (int g = 0; g < 2; ++g) {                                           \
        _Pragma("unroll")                                                     \
        for (int dj = 0; dj < 4; ++dj)                                        \
          accO[g][dj] = __builtin_amdgcn_mfma_f32_16x16x32_bf16(vf[dj], PFR[g][kk].v, accO[g][dj], 0, 0, 0); \
        accS[g] = __builtin_amdgcn_mfma_f32_16x16x32_bf16(ones.v, PFR[g][kk].v, accS[g], 0, 0, 0); \
      }                                                                       \
      __builtin_amdgcn_s_setprio(0);                                          \
    }                                                                         \
  }

  // 32 tiles as 16 pairs; PV lags QK^T by one tile. V slots: stage (k+1)%3,
  // PV (k-1)%3, current k%3 — pairwise distinct mod 3 at every point.
  for (int kp = 0; kp < 16; ++kp) {
    const int k0 = 2 * kp, k1 = k0 + 1;
    KSTAGE(1, k1); VSTAGE(k1 % 3, k1);
    QKT_EXP(pfrA, 0);
    if (kp > 0) PV(pfrB, (k0 - 1) % 3);
    __syncthreads();
    if (k1 + 1 < 32) { KSTAGE(0, k1 + 1); VSTAGE((k1 + 1) % 3, k1 + 1); }
    QKT_EXP(pfrB, 1);
    PV(pfrA, k0 % 3);
    if (k1 + 1 < 32) __syncthreads();
  }
  PV(pfrB, 31 % 3);   // drain
#undef QKT_EXP
#undef PV
#undef KSTAGE
#undef VSTAGE

  const int bb = head >> 4, h = head & (NHEAD - 1);
#pragma unroll
  for (int g = 0; g < 2; ++g) {
    const int sq = qb * 128 + wave * 32 + g * 16 + l15;
    float inv = 1.0f / accS[g][0];
#pragma unroll
    for (int dj = 0; dj < 4; ++dj) {
      uint2 o;
      o.x = cvtpk_bf16(accO[g][dj][0] * inv, accO[g][dj][1] * inv);
      o.y = cvtpk_bf16(accO[g][dj][2] * inv, accO[g][dj][3] * inv);
      *reinterpret_cast<uint2*>(&CTX[((size_t)(bb * SEQ + sq)) * HH + h * HDIM + dj * 16 + l4 * 4]) = o;
    }
  }
}

extern "C" void kernel_launch(void* const* d_in, const int* in_sizes, int n_in,
                              void* d_out, int out_size, void* d_ws, size_t ws_size,
                              hipStream_t stream) {
  const float* hs = (const float*)d_in[0];
  const float* Wq = (const float*)d_in[1];
  const float* bq = (const float*)d_in[2];
  const float* Wk = (const float*)d_in[3];
  const float* bk = (const float*)d_in[4];
  const float* Wv = (const float*)d_in[5];
  const float* bv = (const float*)d_in[6];
  const float* Wo = (const float*)d_in[7];
  const float* bo = (const float*)d_in[8];
  float* out = (float*)d_out;

  char* ws = (char*)d_ws;
  u16* Xb   = (u16*)(ws);                       // 8 MiB (X bf16)
  u16* Wall = (u16*)(ws + ((size_t)8 << 20));   // [Wq|Wk|Wv|Wo] bf16, contiguous after Xb
  u16* Qh   = (u16*)(ws + ((size_t)16 << 20));
  u16* Kh   = (u16*)(ws + ((size_t)24 << 20));
  u16* VT   = (u16*)(ws + ((size_t)32 << 20));
  u16* CT   = Xb;  // X dead after QKV GEMM

  const int nflt4 = MTOT * HH / 4 + HH * HH;    // X + 4 weights, float4 units
  cvt_all_kernel<<<dim3(nflt4 / 256), 256, 0, stream>>>(
      hs, Wq, Wk, Wv, Wo, (u16*)ws);

  gemm_qkv_kernel<<<dim3(MTOT / 128, 3 * HH / 128), 256, 0, stream>>>(
      Xb, Wall, bq, bk, bv, Qh, Kh, VT);

  attn_kernel<<<dim3(NB * NHEAD, SEQ / 128), 256, 0, stream>>>(Qh, Kh, VT, CT);

  gemm_o_kernel<<<dim3(MTOT / 64, HH / 128), 256, 0, stream>>>(
      CT, Wall + (size_t)3 * HH * HH, bo, out);
}